// Round 5
// baseline (424.977 us; speedup 1.0000x reference)
//
#include <hip/hip_runtime.h>
#include <math.h>

#define HW   4096
#define CINP 512
#define LCH  64

typedef short bf8 __attribute__((ext_vector_type(8)));   // 8 bf16 = 4 VGPRs
typedef float f4  __attribute__((ext_vector_type(4)));   // MFMA C/D frag

__device__ __forceinline__ unsigned short f2bf(float x) {
    union { float f; unsigned int u; } v; v.f = x;
    return (unsigned short)((v.u + 0x7fffu + ((v.u >> 16) & 1u)) >> 16);
}
__device__ __forceinline__ bf8 ldbf8(const unsigned short* p) {
    uint4 u = *(const uint4*)p;
    return __builtin_bit_cast(bf8, u);
}

// -------------------------------------------------------------------------
// precast: weights (+gain) and concepts to bf16, concepts also transposed.
// WB[192][512] = [wt;wp;wg]*gain   WO[512][64]   CK[256][64]   CV[64][256]
// -------------------------------------------------------------------------
__global__ __launch_bounds__(256) void precast(
    const float* __restrict__ wt, const float* __restrict__ wp,
    const float* __restrict__ wg, const float* __restrict__ wo,
    const float* __restrict__ conc,
    unsigned short* __restrict__ WB, unsigned short* __restrict__ WO,
    unsigned short* __restrict__ CK, unsigned short* __restrict__ CV)
{
    const float gain = 0.04419417382415922f;  // 1/sqrt(512)
    int id = blockIdx.x * 256 + threadIdx.x;
    if (id < 98304) {
        int o = id >> 9, k = id & 511;
        const float* w = (o < 64) ? wt : (o < 128) ? wp : wg;
        WB[id] = f2bf(w[(o & 63) * 512 + k] * gain);
    } else if (id < 131072) {
        int j = id - 98304;
        WO[j] = f2bf(wo[j]);
    } else if (id < 147456) {
        int j = id - 131072;
        CK[j] = f2bf(conc[j]);
    } else if (id < 163840) {
        int j = id - 147456;
        int l = j >> 8, m = j & 255;
        CV[j] = f2bf(conc[m * 64 + l]);
    }
}

// -------------------------------------------------------------------------
// cast_transpose: f fp32 [b][512][4096] -> XT bf16 [b][4096][512]
// -------------------------------------------------------------------------
__global__ __launch_bounds__(256) void cast_transpose(const float* __restrict__ x,
                                                      unsigned short* __restrict__ XT)
{
    __shared__ unsigned short Lb[64][72];   // [n][c]
    const int t  = threadIdx.x;
    const int n0 = blockIdx.x * 64, c0 = blockIdx.y * 64, b = blockIdx.z;
    const float* xb = x + ((size_t)b * CINP + c0) * HW + n0;
    const int cc = t >> 4, n4 = (t & 15) * 4;
    #pragma unroll
    for (int i = 0; i < 4; i++) {
        int c = cc + i * 16;
        float4 v = *(const float4*)(xb + (size_t)c * HW + n4);
        Lb[n4 + 0][c] = f2bf(v.x);
        Lb[n4 + 1][c] = f2bf(v.y);
        Lb[n4 + 2][c] = f2bf(v.z);
        Lb[n4 + 3][c] = f2bf(v.w);
    }
    __syncthreads();
    const int n = t & 63, cb0 = t >> 6;
    unsigned short* orow = XT + ((size_t)b * HW + n0 + n) * CINP + c0;
    #pragma unroll
    for (int i = 0; i < 2; i++) {
        int cb = cb0 + i * 4;
        *(uint4*)(orow + cb * 8) = *(const uint4*)&Lb[n][cb * 8];
    }
}

// -------------------------------------------------------------------------
// lat_transpose: A bf16 flat [b][4096][64] viewed as lat[b][64][4096]
// (raw reinterpret, the torch .view) -> LT[b][s][c] = lat[b][c][s].
// -------------------------------------------------------------------------
__global__ __launch_bounds__(256) void lat_transpose(const unsigned short* __restrict__ A,
                                                     unsigned short* __restrict__ LT)
{
    __shared__ unsigned short Ls[64][72];
    const int t = threadIdx.x, s0 = blockIdx.x * 64, b = blockIdx.y;
    const unsigned short* ab = A + (size_t)b * LCH * HW;
    #pragma unroll
    for (int it = 0; it < 2; it++) {
        int c = (t >> 3) + it * 32, s8 = (t & 7) * 8;
        union { uint4 u; unsigned short s[8]; } v;
        v.u = *(const uint4*)(ab + (size_t)c * HW + s0 + s8);
        #pragma unroll
        for (int i = 0; i < 8; i++) Ls[s8 + i][c] = v.s[i];
    }
    __syncthreads();
    unsigned short* ob = LT + ((size_t)b * HW + s0) * LCH;
    #pragma unroll
    for (int it = 0; it < 2; it++) {
        int s = (t >> 3) + it * 32, c8 = (t & 7);
        *(uint4*)(ob + (size_t)s * LCH + c8 * 8) = *(const uint4*)&Ls[s][c8 * 8];
    }
}

// -------------------------------------------------------------------------
// qkv_gemm<NRT>: barrier-free, LDS-free; A (weights) and B (XT rows) frags
// direct from global. NRT=12: Q -> XT cols [0,64), K -> [64,128), V -> VL.
// NRT=4: enc -> XT cols [0,64).
// -------------------------------------------------------------------------
template <int NRT>
__global__ __launch_bounds__(256) void qkv_gemm(unsigned short* XT,
                                                const unsigned short* __restrict__ WB,
                                                unsigned short* __restrict__ VL)
{
    const int t = threadIdx.x;
    const int wave = t >> 6, lane = t & 63, quad = lane >> 4, lidx = lane & 15;
    const int b = blockIdx.y;
    const int ncol = blockIdx.x * 64 + wave * 16 + lidx;
    unsigned short* xrow = XT + ((size_t)b * HW + ncol) * CINP;

    f4 acc[NRT];
    #pragma unroll
    for (int r = 0; r < NRT; r++) acc[r] = (f4){0.f, 0.f, 0.f, 0.f};

    for (int kk = 0; kk < 16; kk++) {
        const int k0 = kk * 32 + quad * 8;
        bf8 bq = ldbf8(xrow + k0);
        #pragma unroll
        for (int rt = 0; rt < NRT; rt++) {
            bf8 aw = ldbf8(WB + (size_t)(rt * 16 + lidx) * CINP + k0);
            acc[rt] = __builtin_amdgcn_mfma_f32_16x16x32_bf16(aw, bq, acc[rt], 0, 0, 0);
        }
    }

    #pragma unroll
    for (int rt = 0; rt < NRT; rt++) {
        if (rt < 8) {  // Q (rt<4) and K (rt<8): n-major, in place in XT
            union { unsigned short s[4]; uint2 u; } pk;
            #pragma unroll
            for (int r = 0; r < 4; r++) pk.s[r] = f2bf(acc[rt][r]);
            int off = (rt < 4) ? (rt * 16 + quad * 4) : (64 + (rt - 4) * 16 + quad * 4);
            *(uint2*)(xrow + off) = pk.u;
        } else {       // V: l-major
            #pragma unroll
            for (int r = 0; r < 4; r++) {
                int l = (rt - 8) * 16 + quad * 4 + r;
                VL[((size_t)b * LCH + l) * HW + ncol] = f2bf(acc[rt][r]);
            }
        }
    }
}

// -------------------------------------------------------------------------
// flash: split-K MFMA attention, max-free softmax (exact: O_unnorm and L
// are plain sums over keys). Block = 4 waves; each wave owns nkeys/4 keys
// of the SAME 32 queries; K-loop is barrier-free; O/L merged via LDS at end.
// Per-wave 8704B LDS slice reused: Ps (P roundtrip) in loop, Op (fp32
// partial, pad-68 -> 2-way-free banks) after barrier #1.
// -------------------------------------------------------------------------
__global__ __launch_bounds__(256) void flash(
    const unsigned short* Qb, size_t qbat,
    const unsigned short* Kb, size_t krow, size_t kbat,
    const unsigned short* Vb, size_t vrow, size_t vbat,
    unsigned short* __restrict__ Aout, int nkeys)
{
    __shared__ __align__(16) char smem[4][8704];
    __shared__ float Lw[4][32];

    const int t = threadIdx.x;
    const int wave = t >> 6, lane = t & 63, quad = lane >> 4, lidx = lane & 15;
    const int b = blockIdx.y, q0 = blockIdx.x * 32;
    const int kw = nkeys >> 2;          // keys per wave
    const int kbase = wave * kw;
    const unsigned short* qp = Qb + (size_t)b * qbat;
    const unsigned short* kp = Kb + (size_t)b * kbat;
    const unsigned short* vp = Vb + (size_t)b * vbat;
    unsigned short* psw = (unsigned short*)smem[wave];

    // Q A-frags: row n = q0+qb*16+lidx, k = l = kh*32+quad*8+j
    bf8 qa[2][2];
    #pragma unroll
    for (int qb = 0; qb < 2; qb++)
        #pragma unroll
        for (int kh = 0; kh < 2; kh++)
            qa[qb][kh] = ldbf8(qp + (size_t)(q0 + qb * 16 + lidx) * CINP + kh * 32 + quad * 8);

    f4 O[2][4];
    float Lp[2][4];
    #pragma unroll
    for (int qb = 0; qb < 2; qb++) {
        #pragma unroll
        for (int lt = 0; lt < 4; lt++) O[qb][lt] = (f4){0.f, 0.f, 0.f, 0.f};
        #pragma unroll
        for (int r = 0; r < 4; r++) Lp[qb][r] = 0.f;
    }

    const int ntiles = kw >> 5;
    #pragma unroll 2
    for (int tl = 0; tl < ntiles; tl++) {
        const int m0 = kbase + tl * 32;
        const unsigned short* kr0 = kp + (size_t)(m0 + lidx) * krow + quad * 8;
        const unsigned short* kr1 = kp + (size_t)(m0 + 16 + lidx) * krow + quad * 8;
        bf8 kf00 = ldbf8(kr0), kf01 = ldbf8(kr0 + 32);
        bf8 kf10 = ldbf8(kr1), kf11 = ldbf8(kr1 + 32);

        f4 S[2][2];
        #pragma unroll
        for (int qb = 0; qb < 2; qb++) {
            S[qb][0] = (f4){0.f, 0.f, 0.f, 0.f};
            S[qb][1] = (f4){0.f, 0.f, 0.f, 0.f};
            S[qb][0] = __builtin_amdgcn_mfma_f32_16x16x32_bf16(qa[qb][0], kf00, S[qb][0], 0, 0, 0);
            S[qb][0] = __builtin_amdgcn_mfma_f32_16x16x32_bf16(qa[qb][1], kf01, S[qb][0], 0, 0, 0);
            S[qb][1] = __builtin_amdgcn_mfma_f32_16x16x32_bf16(qa[qb][0], kf10, S[qb][1], 0, 0, 0);
            S[qb][1] = __builtin_amdgcn_mfma_f32_16x16x32_bf16(qa[qb][1], kf11, S[qb][1], 0, 0, 0);
        }

        // P = exp(S) (scores bounded ~|50|), L partials per lane
        const int pb = (tl & 1) * 32;
        #pragma unroll
        for (int qb = 0; qb < 2; qb++)
            #pragma unroll
            for (int ms = 0; ms < 2; ms++)
                #pragma unroll
                for (int r = 0; r < 4; r++) {
                    float p = __expf(S[qb][ms][r]);
                    Lp[qb][r] += p;
                    psw[(pb + qb * 16 + quad * 4 + r) * 40 + ms * 16 + lidx] = f2bf(p);
                }

        bf8 pf0 = *(const bf8*)&psw[(pb + lidx) * 40 + quad * 8];
        bf8 pf1 = *(const bf8*)&psw[(pb + 16 + lidx) * 40 + quad * 8];

        #pragma unroll
        for (int lt = 0; lt < 4; lt++) {
            bf8 vf = ldbf8(vp + (size_t)(lt * 16 + lidx) * vrow + m0 + quad * 8);
            O[0][lt] = __builtin_amdgcn_mfma_f32_16x16x32_bf16(pf0, vf, O[0][lt], 0, 0, 0);
            O[1][lt] = __builtin_amdgcn_mfma_f32_16x16x32_bf16(pf1, vf, O[1][lt], 0, 0, 0);
        }
    }

    // per-wave row L partials (reduce over lidx group), write to Lw
    #pragma unroll
    for (int qb = 0; qb < 2; qb++)
        #pragma unroll
        for (int r = 0; r < 4; r++) {
            float s = Lp[qb][r];
            s += __shfl_xor(s, 1);
            s += __shfl_xor(s, 2);
            s += __shfl_xor(s, 4);
            s += __shfl_xor(s, 8);
            if (lidx == 0) Lw[wave][qb * 16 + quad * 4 + r] = s;
        }

    __syncthreads();   // all Ps reads complete -> slice reusable as Op

    float* opw = (float*)smem[wave];
    #pragma unroll
    for (int qb = 0; qb < 2; qb++)
        #pragma unroll
        for (int lt = 0; lt < 4; lt++)
            #pragma unroll
            for (int r = 0; r < 4; r++)
                opw[(qb * 16 + quad * 4 + r) * 68 + lt * 16 + lidx] = O[qb][lt][r];

    __syncthreads();   // partials visible -> merge

    const int n = t >> 3, l0 = (t & 7) * 8;
    const float inv = 1.f / (Lw[0][n] + Lw[1][n] + Lw[2][n] + Lw[3][n]);
    float a0 = 0.f, a1 = 0.f, a2 = 0.f, a3 = 0.f, a4 = 0.f, a5 = 0.f, a6 = 0.f, a7 = 0.f;
    #pragma unroll
    for (int w = 0; w < 4; w++) {
        const float* row = (const float*)smem[w] + n * 68 + l0;
        float4 u = *(const float4*)row;
        float4 v = *(const float4*)(row + 4);
        a0 += u.x; a1 += u.y; a2 += u.z; a3 += u.w;
        a4 += v.x; a5 += v.y; a6 += v.z; a7 += v.w;
    }
    union { unsigned short s[8]; uint4 u; } pk;
    pk.s[0] = f2bf(a0 * inv); pk.s[1] = f2bf(a1 * inv);
    pk.s[2] = f2bf(a2 * inv); pk.s[3] = f2bf(a3 * inv);
    pk.s[4] = f2bf(a4 * inv); pk.s[5] = f2bf(a5 * inv);
    pk.s[6] = f2bf(a6 * inv); pk.s[7] = f2bf(a7 * inv);
    *(uint4*)(Aout + ((size_t)b * HW + q0 + n) * LCH + l0) = pk.u;
}

// -------------------------------------------------------------------------
// conv_o: out[b,o,s] = gamma/8 * sum_c WO[o,c]*LT[s,c] + res[b,o,s]
// LT: bf16 [b][4096][64] with LT[s][c] = lat[c][s] (lat_transpose output).
// Optionally emits ST bf16 [b][s][512] (transposed sa_out for stage-2).
// -------------------------------------------------------------------------
__global__ __launch_bounds__(256) void conv_o(const unsigned short* __restrict__ LT,
                                              const unsigned short* __restrict__ WO,
                                              const float* __restrict__ res,
                                              const float* __restrict__ gamma_p,
                                              float* __restrict__ out,
                                              unsigned short* ST)
{
    const int t = threadIdx.x;
    const int wave = t >> 6, lane = t & 63, quad = lane >> 4, lidx = lane & 15;
    const int b = blockIdx.z, o0 = blockIdx.y * 64;
    const int scol = blockIdx.x * 64 + wave * 16 + lidx;
    const unsigned short* arow = LT + ((size_t)b * HW + scol) * LCH;

    f4 acc[4];
    #pragma unroll
    for (int ot = 0; ot < 4; ot++) acc[ot] = (f4){0.f, 0.f, 0.f, 0.f};

    #pragma unroll
    for (int kh = 0; kh < 2; kh++) {
        bf8 bq = ldbf8(arow + kh * 32 + quad * 8);
        #pragma unroll
        for (int ot = 0; ot < 4; ot++) {
            bf8 af = ldbf8(WO + (size_t)(o0 + ot * 16 + lidx) * LCH + kh * 32 + quad * 8);
            acc[ot] = __builtin_amdgcn_mfma_f32_16x16x32_bf16(af, bq, acc[ot], 0, 0, 0);
        }
    }

    const float scale = gamma_p[0] * 0.125f;  // gamma * 1/sqrt(64)
    #pragma unroll
    for (int ot = 0; ot < 4; ot++) {
        float v[4];
        #pragma unroll
        for (int r = 0; r < 4; r++) {
            size_t idx = ((size_t)b * CINP + o0 + ot * 16 + quad * 4 + r) * HW + scol;
            v[r] = fmaf(scale, acc[ot][r], res[idx]);
            out[idx] = v[r];
        }
        if (ST) {
            union { unsigned short s[4]; uint2 u; } pk;
            #pragma unroll
            for (int r = 0; r < 4; r++) pk.s[r] = f2bf(v[r]);
            *(uint2*)(ST + ((size_t)b * HW + scol) * CINP + o0 + ot * 16 + quad * 4) = pk.u;
        }
    }
}

// -------------------------------------------------------------------------
extern "C" void kernel_launch(void* const* d_in, const int* in_sizes, int n_in,
                              void* d_out, int out_size, void* d_ws, size_t ws_size,
                              hipStream_t stream)
{
    const float* f    = (const float*)d_in[0];
    const float* conc = (const float*)d_in[1];
    const float* wt   = (const float*)d_in[2];
    const float* wp   = (const float*)d_in[3];
    const float* wg   = (const float*)d_in[4];
    const float* wo   = (const float*)d_in[5];
    const float* gsa  = (const float*)d_in[6];
    const float* gmo  = (const float*)d_in[7];
    float* out = (float*)d_out;

    // ws layout (~40.4 MiB):
    //  [0, 32M)   XT bf16 [8][4096][512]; Q/K in place -> later ST + Q2 in place
    //  [32M,36M)  VL bf16 [8][64][4096]  -> later LT (lat transposed)
    //  [36M,40M)  A1/A2 bf16 [8][4096][64] (attention out, n-major)
    //  [40M,...)  WB WO CK CV bf16
    char* ws = (char*)d_ws;
    unsigned short* XT = (unsigned short*)ws;
    unsigned short* VL = (unsigned short*)(ws + ((size_t)32 << 20));
    unsigned short* LT = VL;  // reuse after flash1
    unsigned short* A1 = (unsigned short*)(ws + ((size_t)36 << 20));
    unsigned short* WB = (unsigned short*)(ws + ((size_t)40 << 20));
    unsigned short* WO = WB + 192 * 512;
    unsigned short* CK = WO + 512 * 64;
    unsigned short* CV = CK + 256 * 64;

    dim3 blk256(256), blk64(64);

    precast<<<640, blk256, 0, stream>>>(wt, wp, wg, wo, conc, WB, WO, CK, CV);
    cast_transpose<<<dim3(64, 8, 8), blk256, 0, stream>>>(f, XT);

    // ---- SelfAttention ----
    qkv_gemm<12><<<dim3(64, 8), blk256, 0, stream>>>(XT, WB, VL);
    flash<<<dim3(128, 8), blk256, 0, stream>>>(
        XT, (size_t)HW * CINP,
        XT + 64, CINP, (size_t)HW * CINP,
        VL, HW, (size_t)LCH * HW,
        A1, HW);
    lat_transpose<<<dim3(64, 8), blk256, 0, stream>>>(A1, LT);
    conv_o<<<dim3(64, 8, 8), blk256, 0, stream>>>(LT, WO, f, gsa, out, XT /*emit ST*/);

    // ---- MomentumConceptAttention ----
    qkv_gemm<4><<<dim3(64, 8), blk256, 0, stream>>>(XT /*=ST*/, WB /*wt rows*/, nullptr);
    flash<<<dim3(128, 8), blk256, 0, stream>>>(
        XT, (size_t)HW * CINP,
        CK, LCH, 0,
        CV, 256, 0,
        A1 /*=A2*/, 256);
    lat_transpose<<<dim3(64, 8), blk256, 0, stream>>>(A1, LT);
    conv_o<<<dim3(64, 8, 8), blk256, 0, stream>>>(LT, WO, out, gmo, out, nullptr);
}